// Round 4
// baseline (810.092 us; speedup 1.0000x reference)
//
#include <hip/hip_runtime.h>
#include <cstdint>

#define EPS 1e-5f

typedef __attribute__((ext_vector_type(8))) short bf16x8;   // 8 bf16 in 4 VGPRs
typedef __attribute__((ext_vector_type(4))) float f32x4;

// ---------- bf16 helpers (RNE) ----------
__device__ __forceinline__ unsigned short f2bf(float x) {
    uint32_t u = __float_as_uint(x);
    u += 0x7fffu + ((u >> 16) & 1u);
    return (unsigned short)(u >> 16);
}
__device__ __forceinline__ uint32_t pack2(float lo, float hi) {
    return (uint32_t)f2bf(lo) | ((uint32_t)f2bf(hi) << 16);
}
__device__ __forceinline__ float bflo(uint32_t p) { return __uint_as_float(p << 16); }
__device__ __forceinline__ float bfhi(uint32_t p) { return __uint_as_float(p & 0xffff0000u); }

// ---------- CSR build ----------
__global__ __launch_bounds__(256) void zero_kernel(int* __restrict__ p, int n) {
    int i = blockIdx.x * 256 + threadIdx.x;
    if (i < n) p[i] = 0;
}

__global__ __launch_bounds__(256) void count_kernel(const int* __restrict__ ei,
                                                    int* __restrict__ deg, int E) {
    int e = blockIdx.x * 256 + threadIdx.x;
    if (e < E) atomicAdd(&deg[ei[E + e]], 1);
}

__global__ __launch_bounds__(1024) void scan_kernel(const int* __restrict__ deg,
                                                    int* __restrict__ offsets,
                                                    int* __restrict__ cursor,
                                                    float* __restrict__ deginv, int N) {
    __shared__ int part[1024];
    const int t = threadIdx.x;
    const int CH = (N + 1023) >> 10;
    const int base = t * CH;
    int s = 0;
    for (int j = 0; j < CH; ++j) {
        int idx = base + j;
        if (idx < N) s += deg[idx];
    }
    part[t] = s;
    __syncthreads();
    for (int off = 1; off < 1024; off <<= 1) {
        int add = (t >= off) ? part[t - off] : 0;
        __syncthreads();
        part[t] += add;
        __syncthreads();
    }
    int run = (t == 0) ? 0 : part[t - 1];
    for (int j = 0; j < CH; ++j) {
        int idx = base + j;
        if (idx < N) {
            offsets[idx] = run;
            cursor[idx]  = run;
            int dgi = deg[idx];
            deginv[idx] = 1.0f / (float)(dgi > 0 ? dgi : 1);
            run += dgi;
        }
    }
    if (t == 1023) offsets[N] = run;
}

__global__ __launch_bounds__(256) void fill_kernel(const int* __restrict__ ei,
                                                   int* __restrict__ cursor,
                                                   int* __restrict__ csr, int E) {
    int e = blockIdx.x * 256 + threadIdx.x;
    if (e < E) {
        int dd = ei[E + e];
        int slot = atomicAdd(&cursor[dd], 1);
        csr[slot] = ei[e];
    }
}

// ---------- embedding + BN(layer 0), bf16 into X[N][512] ----------
__global__ __launch_bounds__(256) void embed_bn_kernel(const int* __restrict__ tok,
                                                       const int* __restrict__ pos,
                                                       const float* __restrict__ vemb,
                                                       const float* __restrict__ pemb,
                                                       const float* __restrict__ gamma,
                                                       const float* __restrict__ beta,
                                                       const float* __restrict__ mean,
                                                       const float* __restrict__ var,
                                                       uint32_t* __restrict__ X, int N) {
    const int idx = blockIdx.x * 256 + threadIdx.x;
    if (idx >= N * 128) return;
    const int row = idx >> 7;
    const int c = (idx & 127) * 4;
    const int tk = tok[row];
    const int ps = pos[row];
    const float4 a = *(const float4*)&vemb[(size_t)tk * 512 + c];
    const float4 b = *(const float4*)&pemb[(size_t)ps * 512 + c];
    const float4 g = *(const float4*)&gamma[c];
    const float4 be = *(const float4*)&beta[c];
    const float4 mn = *(const float4*)&mean[c];
    const float4 vr = *(const float4*)&var[c];
    const float y0 = (a.x + b.x - mn.x) * (g.x * rsqrtf(vr.x + EPS)) + be.x;
    const float y1 = (a.y + b.y - mn.y) * (g.y * rsqrtf(vr.y + EPS)) + be.y;
    const float y2 = (a.z + b.z - mn.z) * (g.z * rsqrtf(vr.z + EPS)) + be.z;
    const float y3 = (a.w + b.w - mn.w) * (g.w * rsqrtf(vr.w + EPS)) + be.w;
    uint2 o;
    o.x = pack2(y0, y1);
    o.y = pack2(y2, y3);
    *(uint2*)&X[(size_t)row * 256 + (c >> 1)] = o;
}

// ---------- per-layer: W_cat bf16 [512 rows][1024 k] = [W_root | W_rel] (B^T layout) ----------
__global__ __launch_bounds__(256) void castW_kernel(const float* __restrict__ Wroot,
                                                    const float* __restrict__ Wrel,
                                                    uint32_t* __restrict__ Wcat) {
    const int p = blockIdx.x * 256 + threadIdx.x;
    const int o  = p >> 9;
    const int dp = p & 511;
    float2 v;
    if (dp < 256) v = *(const float2*)&Wroot[(size_t)o * 512 + dp * 2];
    else          v = *(const float2*)&Wrel[(size_t)o * 512 + (dp - 256) * 2];
    Wcat[(size_t)o * 512 + dp] = pack2(v.x, v.y);
}

// ---------- mean aggregation (CSR gather, wave-per-node): G[i] = mean_{j->i} X[j] ----------
__global__ __launch_bounds__(256) void aggregate_kernel(const uint32_t* __restrict__ X,
                                                        uint32_t* __restrict__ G,
                                                        const int* __restrict__ offsets,
                                                        const int* __restrict__ csr,
                                                        const float* __restrict__ deginv,
                                                        int N) {
    const int node = blockIdx.x * 4 + (threadIdx.x >> 6);
    if (node >= N) return;
    const int lane = threadIdx.x & 63;
    const int col = lane * 4;
    const int beg = offsets[node];
    const int end = offsets[node + 1];
    float s[8] = {0.f, 0.f, 0.f, 0.f, 0.f, 0.f, 0.f, 0.f};
    int e = beg;
    for (; e + 8 <= end; e += 8) {
        uint4 p[8];
#pragma unroll
        for (int j = 0; j < 8; ++j) {
            const int ij = csr[e + j];
            p[j] = *(const uint4*)&X[(size_t)ij * 256 + col];
        }
#pragma unroll
        for (int j = 0; j < 8; ++j) {
            s[0] += bflo(p[j].x); s[1] += bfhi(p[j].x);
            s[2] += bflo(p[j].y); s[3] += bfhi(p[j].y);
            s[4] += bflo(p[j].z); s[5] += bfhi(p[j].z);
            s[6] += bflo(p[j].w); s[7] += bfhi(p[j].w);
        }
    }
    for (; e < end; ++e) {
        const int i0 = csr[e];
        const uint4 p0 = *(const uint4*)&X[(size_t)i0 * 256 + col];
        s[0] += bflo(p0.x); s[1] += bfhi(p0.x);
        s[2] += bflo(p0.y); s[3] += bfhi(p0.y);
        s[4] += bflo(p0.z); s[5] += bfhi(p0.z);
        s[6] += bflo(p0.w); s[7] += bfhi(p0.w);
    }
    const float inv = deginv[node];
    uint4 o;
    o.x = pack2(s[0] * inv, s[1] * inv);
    o.y = pack2(s[2] * inv, s[3] * inv);
    o.z = pack2(s[4] * inv, s[5] * inv);
    o.w = pack2(s[6] * inv, s[7] * inv);
    *(uint4*)&G[(size_t)node * 256 + col] = o;
}

// ---------- register-direct GEMM, no LDS, no barriers ----------
// out[M,512] = relu([X|G][M,1024] @ Wcat[512,1024]^T + bias); X,G are [M][512] bf16.
// Per wave: 64x64 tile via 4x4 MFMA(16x16x32). Fragments loaded straight from
// global (16 B/lane = one dwordx4; a wave covers 16 rows x 64 B, full lines).
// K pipelined with a 2-stage register double buffer; loads overlap MFMA freely
// since there are no block-level syncs (this removes the m97 barrier stall).
__global__ __launch_bounds__(256) void gemm_reg_bias_relu(const unsigned short* __restrict__ X,
                                                          const unsigned short* __restrict__ G,
                                                          const unsigned short* __restrict__ B,
                                                          const float* __restrict__ bias,
                                                          const float* __restrict__ gamma,
                                                          const float* __restrict__ beta,
                                                          const float* __restrict__ mean,
                                                          const float* __restrict__ var,
                                                          int last,
                                                          float* __restrict__ C,
                                                          unsigned short* __restrict__ Y,
                                                          int M) {
    const int t    = threadIdx.x;
    const int lane = t & 63;
    const int wave = t >> 6;
    const int lm = lane & 15;
    const int q  = lane >> 4;
    const int bm = blockIdx.y;
    const int bn = blockIdx.x;
    const int wn = bn * 256 + wave * 64;   // this wave's 64 output cols

    uint32_t aoff[4], boff[4];
#pragma unroll
    for (int mt = 0; mt < 4; ++mt) {
        int r = bm * 64 + mt * 16 + lm;
        if (r >= M) r = M - 1;
        aoff[mt] = (uint32_t)r * 512u + q * 8u;        // X/G row stride 512 shorts
    }
#pragma unroll
    for (int nt = 0; nt < 4; ++nt)
        boff[nt] = (uint32_t)(wn + nt * 16 + lm) * 1024u + q * 8u;  // Wcat stride 1024

    const f32x4 zero = {0.f, 0.f, 0.f, 0.f};
    f32x4 acc[4][4];
#pragma unroll
    for (int i = 0; i < 4; ++i)
#pragma unroll
        for (int j = 0; j < 4; ++j) acc[i][j] = zero;

#define LOADA(P, av, K0) { _Pragma("unroll") for (int i_ = 0; i_ < 4; ++i_) \
        av[i_] = *(const bf16x8*)((P) + aoff[i_] + (K0)); }
#define LOADB(bv, K0) { _Pragma("unroll") for (int i_ = 0; i_ < 4; ++i_) \
        bv[i_] = *(const bf16x8*)(B + boff[i_] + (K0)); }
#define MFMA16(av, bv) { _Pragma("unroll") for (int mt_ = 0; mt_ < 4; ++mt_) \
        _Pragma("unroll") for (int nt_ = 0; nt_ < 4; ++nt_) \
            acc[mt_][nt_] = __builtin_amdgcn_mfma_f32_16x16x32_bf16(av[mt_], bv[nt_], acc[mt_][nt_], 0, 0, 0); }

    // phase 1: k = 0..511 from X (x Wroot half); phase 2: k = 512..1023 from G (x Wrel half)
#pragma unroll
    for (int ph = 0; ph < 2; ++ph) {
        const unsigned short* P = ph ? G : X;
        const int kb = ph * 512;
        bf16x8 a0[4], b0[4], a1[4], b1[4];
        LOADA(P, a0, 0); LOADB(b0, kb);
        for (int k0 = 0; k0 < 448; k0 += 64) {
            LOADA(P, a1, k0 + 32); LOADB(b1, kb + k0 + 32);
            MFMA16(a0, b0);
            LOADA(P, a0, k0 + 64); LOADB(b0, kb + k0 + 64);
            MFMA16(a1, b1);
        }
        LOADA(P, a1, 480); LOADB(b1, kb + 480);
        MFMA16(a0, b0);
        MFMA16(a1, b1);
    }

    // epilogue: C/D layout col=lane&15, row=(lane>>4)*4+reg (m89-verified)
#pragma unroll
    for (int nt = 0; nt < 4; ++nt) {
        const int col = wn + nt * 16 + lm;
        const float bv = bias[col];
        float bn_inv = 0.f, bn_mb = 0.f, bn_beta = 0.f;
        if (!last) {
            bn_inv = gamma[col] * rsqrtf(var[col] + EPS);
            bn_mb  = mean[col];
            bn_beta = beta[col];
        }
#pragma unroll
        for (int mt = 0; mt < 4; ++mt) {
            const int row0 = bm * 64 + mt * 16 + q * 4;
#pragma unroll
            for (int i = 0; i < 4; ++i) {
                const int row = row0 + i;
                if (row < M) {
                    float v = acc[mt][nt][i] + bv;
                    v = v > 0.f ? v : 0.f;
                    if (last) {
                        C[(size_t)row * 512 + col] = v;
                    } else {
                        const float y = (v - bn_mb) * bn_inv + bn_beta;
                        Y[(size_t)row * 512 + col] = f2bf(y);
                    }
                }
            }
        }
    }
#undef LOADA
#undef LOADB
#undef MFMA16
}

extern "C" void kernel_launch(void* const* d_in, const int* in_sizes, int n_in,
                              void* d_out, int out_size, void* d_ws, size_t ws_size,
                              hipStream_t stream) {
    const int*   tokens = (const int*)d_in[0];
    const int*   posi   = (const int*)d_in[1];
    const int*   ei     = (const int*)d_in[2];
    const float* vemb   = (const float*)d_in[3];
    const float* pemb   = (const float*)d_in[4];
    const float* gamma  = (const float*)d_in[5];
    const float* beta   = (const float*)d_in[6];
    const float* mean   = (const float*)d_in[7];
    const float* var    = (const float*)d_in[8];
    const float* Wrel   = (const float*)d_in[9];
    const float* brel   = (const float*)d_in[10];
    const float* Wroot  = (const float*)d_in[11];

    const int N = in_sizes[0];
    const int E = in_sizes[2] / 2;
    float* out = (float*)d_out;

    // layout: front (CSR) | X0 | G | Wcat | [X1 if ws permits]
    char* w = (char*)d_ws;
    int*      deg     = (int*)(w);
    int*      offsets = (int*)(w + 80000);
    int*      cursor  = (int*)(w + 160016);
    float*    deginv  = (float*)(w + 240032);
    int*      csr     = (int*)(w + 320048);
    uint32_t* X0      = (uint32_t*)(w + 1600064);   // [N][256] uints = [N][512] bf16
    uint32_t* G       = (uint32_t*)(w + 22080064);  // [N][256] uints
    uint32_t* Wcat    = (uint32_t*)(w + 42560064);  // [512][512] uints = [512][1024] bf16
    uint32_t* X1      = (uint32_t*)(w + 43608640);  // second X buffer (ping-pong)
    const bool big = ws_size >= (size_t)43608640 + 20480000;

    zero_kernel<<<(N + 255) / 256, 256, 0, stream>>>(deg, N);
    count_kernel<<<(E + 255) / 256, 256, 0, stream>>>(ei, deg, E);
    scan_kernel<<<1, 1024, 0, stream>>>(deg, offsets, cursor, deginv, N);
    fill_kernel<<<(E + 255) / 256, 256, 0, stream>>>(ei, cursor, csr, E);

    embed_bn_kernel<<<(N * 128 + 255) / 256, 256, 0, stream>>>(
        tokens, posi, vemb, pemb, gamma, beta, mean, var, X0, N);

    uint32_t* X = X0;
    uint32_t* Y = big ? X1 : X0;    // fallback: in-place (pre-R4 behavior) if ws too small
    for (int l = 0; l < 4; ++l) {
        const int last = (l == 3);
        castW_kernel<<<1024, 256, 0, stream>>>(Wroot + (size_t)l * 262144,
                                               Wrel + (size_t)l * 262144, Wcat);
        aggregate_kernel<<<(N + 3) / 4, 256, 0, stream>>>(X, G, offsets, csr, deginv, N);
        gemm_reg_bias_relu<<<dim3(2, (N + 63) / 64), 256, 0, stream>>>(
            (const unsigned short*)X, (const unsigned short*)G,
            (const unsigned short*)Wcat, brel + l * 512,
            gamma + (l + 1) * 512, beta + (l + 1) * 512,
            mean + (l + 1) * 512, var + (l + 1) * 512,
            last, out, (unsigned short*)Y, N);
        uint32_t* tmp = X; X = Y; Y = tmp;
    }
}

// Round 6
// 639.970 us; speedup vs baseline: 1.2658x; 1.2658x over previous
//
#include <hip/hip_runtime.h>
#include <cstdint>

#define EPS 1e-5f

typedef __attribute__((ext_vector_type(8))) short bf16x8;   // 8 bf16 in 4 VGPRs
typedef __attribute__((ext_vector_type(4))) float f32x4;

// ---------- bf16 helpers (RNE) ----------
__device__ __forceinline__ unsigned short f2bf(float x) {
    uint32_t u = __float_as_uint(x);
    u += 0x7fffu + ((u >> 16) & 1u);
    return (unsigned short)(u >> 16);
}
__device__ __forceinline__ uint32_t pack2(float lo, float hi) {
    return (uint32_t)f2bf(lo) | ((uint32_t)f2bf(hi) << 16);
}
__device__ __forceinline__ float bflo(uint32_t p) { return __uint_as_float(p << 16); }
__device__ __forceinline__ float bfhi(uint32_t p) { return __uint_as_float(p & 0xffff0000u); }

// ---------- async global->LDS, 16B per lane ----------
__device__ __forceinline__ void async_ld16(const void* g, const void* l) {
    __builtin_amdgcn_global_load_lds(
        (const __attribute__((address_space(1))) uint32_t*)(uintptr_t)g,
        (__attribute__((address_space(3))) uint32_t*)(uint32_t)(uintptr_t)l,
        16, 0, 0);
}

// ---------- CSR build ----------
__global__ __launch_bounds__(256) void zero_kernel(int* __restrict__ p, int n) {
    int i = blockIdx.x * 256 + threadIdx.x;
    if (i < n) p[i] = 0;
}

__global__ __launch_bounds__(256) void count_kernel(const int* __restrict__ ei,
                                                    int* __restrict__ deg, int E) {
    int e = blockIdx.x * 256 + threadIdx.x;
    if (e < E) atomicAdd(&deg[ei[E + e]], 1);
}

__global__ __launch_bounds__(1024) void scan_kernel(const int* __restrict__ deg,
                                                    int* __restrict__ offsets,
                                                    int* __restrict__ cursor,
                                                    float* __restrict__ deginv, int N) {
    __shared__ int part[1024];
    const int t = threadIdx.x;
    const int CH = (N + 1023) >> 10;
    const int base = t * CH;
    int s = 0;
    for (int j = 0; j < CH; ++j) {
        int idx = base + j;
        if (idx < N) s += deg[idx];
    }
    part[t] = s;
    __syncthreads();
    for (int off = 1; off < 1024; off <<= 1) {
        int add = (t >= off) ? part[t - off] : 0;
        __syncthreads();
        part[t] += add;
        __syncthreads();
    }
    int run = (t == 0) ? 0 : part[t - 1];
    for (int j = 0; j < CH; ++j) {
        int idx = base + j;
        if (idx < N) {
            offsets[idx] = run;
            cursor[idx]  = run;
            int dgi = deg[idx];
            deginv[idx] = 1.0f / (float)(dgi > 0 ? dgi : 1);
            run += dgi;
        }
    }
    if (t == 1023) offsets[N] = run;
}

__global__ __launch_bounds__(256) void fill_kernel(const int* __restrict__ ei,
                                                   int* __restrict__ cursor,
                                                   int* __restrict__ csr, int E) {
    int e = blockIdx.x * 256 + threadIdx.x;
    if (e < E) {
        int dd = ei[E + e];
        int slot = atomicAdd(&cursor[dd], 1);
        csr[slot] = ei[e];
    }
}

// ---------- embedding + BN(layer 0), bf16 into X[N][512] ----------
__global__ __launch_bounds__(256) void embed_bn_kernel(const int* __restrict__ tok,
                                                       const int* __restrict__ pos,
                                                       const float* __restrict__ vemb,
                                                       const float* __restrict__ pemb,
                                                       const float* __restrict__ gamma,
                                                       const float* __restrict__ beta,
                                                       const float* __restrict__ mean,
                                                       const float* __restrict__ var,
                                                       uint32_t* __restrict__ X, int N) {
    const int idx = blockIdx.x * 256 + threadIdx.x;
    if (idx >= N * 128) return;
    const int row = idx >> 7;
    const int c = (idx & 127) * 4;
    const int tk = tok[row];
    const int ps = pos[row];
    const float4 a = *(const float4*)&vemb[(size_t)tk * 512 + c];
    const float4 b = *(const float4*)&pemb[(size_t)ps * 512 + c];
    const float4 g = *(const float4*)&gamma[c];
    const float4 be = *(const float4*)&beta[c];
    const float4 mn = *(const float4*)&mean[c];
    const float4 vr = *(const float4*)&var[c];
    const float y0 = (a.x + b.x - mn.x) * (g.x * rsqrtf(vr.x + EPS)) + be.x;
    const float y1 = (a.y + b.y - mn.y) * (g.y * rsqrtf(vr.y + EPS)) + be.y;
    const float y2 = (a.z + b.z - mn.z) * (g.z * rsqrtf(vr.z + EPS)) + be.z;
    const float y3 = (a.w + b.w - mn.w) * (g.w * rsqrtf(vr.w + EPS)) + be.w;
    uint2 o;
    o.x = pack2(y0, y1);
    o.y = pack2(y2, y3);
    *(uint2*)&X[(size_t)row * 256 + (c >> 1)] = o;
}

// ---------- per-layer: W_cat bf16 [512 rows][1024 k] = [W_root | W_rel] (B^T layout) ----------
__global__ __launch_bounds__(256) void castW_kernel(const float* __restrict__ Wroot,
                                                    const float* __restrict__ Wrel,
                                                    uint32_t* __restrict__ Wcat) {
    const int p = blockIdx.x * 256 + threadIdx.x;
    const int o  = p >> 9;
    const int dp = p & 511;
    float2 v;
    if (dp < 256) v = *(const float2*)&Wroot[(size_t)o * 512 + dp * 2];
    else          v = *(const float2*)&Wrel[(size_t)o * 512 + (dp - 256) * 2];
    Wcat[(size_t)o * 512 + dp] = pack2(v.x, v.y);
}

// ---------- mean aggregation, XCD feature-sliced (FIXED: rows are 256 uints) ----------
// slice = blockIdx.x % 8 -> round-robin XCD dispatch; each XCD touches one
// 32-uint (64-col) slice of X: 20000*128B = 2.56 MB -> L2-resident.
// Wave = one node: 8 edges/iter (8 lanes x uint4 per edge), 2x unrolled,
// cross-sub combine via shfl_xor 8/16/32.
__global__ __launch_bounds__(256) void aggregate_kernel(const uint32_t* __restrict__ X,
                                                        uint32_t* __restrict__ G,
                                                        const int* __restrict__ offsets,
                                                        const int* __restrict__ csr,
                                                        const float* __restrict__ deginv,
                                                        int N) {
    const int slice = blockIdx.x & 7;
    const int ng    = blockIdx.x >> 3;
    const int wave  = threadIdx.x >> 6;
    const int node  = ng * 4 + wave;
    if (node >= N) return;
    const int lane = threadIdx.x & 63;
    const int sub  = lane >> 3;            // which of 8 edges this lane serves
    const int li   = lane & 7;             // 16-B chunk within the 128-B slice
    const int col  = slice * 32 + li * 4;  // uint index in the 256-uint row (max 255)

    const int beg = offsets[node];
    const int end = offsets[node + 1];
    float s[8] = {0.f, 0.f, 0.f, 0.f, 0.f, 0.f, 0.f, 0.f};
    int e = beg;
    for (; e + 16 <= end; e += 16) {
        const int i0 = csr[e + sub];
        const int i1 = csr[e + 8 + sub];
        const uint4 p0 = *(const uint4*)&X[(size_t)i0 * 256 + col];
        const uint4 p1 = *(const uint4*)&X[(size_t)i1 * 256 + col];
        s[0] += bflo(p0.x) + bflo(p1.x); s[1] += bfhi(p0.x) + bfhi(p1.x);
        s[2] += bflo(p0.y) + bflo(p1.y); s[3] += bfhi(p0.y) + bfhi(p1.y);
        s[4] += bflo(p0.z) + bflo(p1.z); s[5] += bfhi(p0.z) + bfhi(p1.z);
        s[6] += bflo(p0.w) + bflo(p1.w); s[7] += bfhi(p0.w) + bfhi(p1.w);
    }
    for (; e < end; e += 8) {
        const int eidx = e + sub;
        uint4 p = {0u, 0u, 0u, 0u};
        if (eidx < end) {
            const int src = csr[eidx];
            p = *(const uint4*)&X[(size_t)src * 256 + col];
        }
        s[0] += bflo(p.x); s[1] += bfhi(p.x);
        s[2] += bflo(p.y); s[3] += bfhi(p.y);
        s[4] += bflo(p.z); s[5] += bfhi(p.z);
        s[6] += bflo(p.w); s[7] += bfhi(p.w);
    }
#pragma unroll
    for (int k = 0; k < 8; ++k) {
        s[k] += __shfl_xor(s[k], 8, 64);
        s[k] += __shfl_xor(s[k], 16, 64);
        s[k] += __shfl_xor(s[k], 32, 64);
    }
    if (sub == 0) {
        const float inv = deginv[node];
        uint4 o;
        o.x = pack2(s[0] * inv, s[1] * inv);
        o.y = pack2(s[2] * inv, s[3] * inv);
        o.z = pack2(s[4] * inv, s[5] * inv);
        o.w = pack2(s[6] * inv, s[7] * inv);
        *(uint4*)&G[(size_t)node * 256 + col] = o;
    }
}

// ---------- GEMM: out = relu([X|G][M,1024] @ Wcat[512,1024]^T + bias) ----------
// 128x128 tile, BK=64 as two proven BK=32 stages per barrier pair (32 KB LDS).
__global__ __launch_bounds__(256) void gemm_bt_bias_relu(const unsigned short* __restrict__ X,
                                                         const unsigned short* __restrict__ G,
                                                         const unsigned short* __restrict__ B,
                                                         const float* __restrict__ bias,
                                                         const float* __restrict__ gamma,
                                                         const float* __restrict__ beta,
                                                         const float* __restrict__ mean,
                                                         const float* __restrict__ var,
                                                         int last,
                                                         float* __restrict__ C,
                                                         unsigned short* __restrict__ Y,
                                                         int M) {
    __shared__ __align__(16) unsigned short As[2 * 128 * 32];   // stage s at +s*4096 shorts
    __shared__ __align__(16) unsigned short Bs[2 * 128 * 32];

    const int t    = threadIdx.x;
    const int lane = t & 63;
    const int wave = t >> 6;
    const int wm = (wave >> 1) * 64;
    const int wn = (wave & 1) * 64;
    const int bm = blockIdx.y;
    const int bn = blockIdx.x;

    const int r  = t >> 2;   // 0..63
    const int kc = t & 3;
    int ar0 = bm * 128 + r;      if (ar0 >= M) ar0 = M - 1;
    int ar1 = bm * 128 + r + 64; if (ar1 >= M) ar1 = M - 1;
    const int br0 = bn * 128 + r;
    const int br1 = br0 + 64;

    unsigned short* la0 = &As[r * 32 + kc * 8];          // byte off t*16 (+s*8192 per stage)
    unsigned short* la1 = &As[(r + 64) * 32 + kc * 8];
    unsigned short* lb0 = &Bs[r * 32 + kc * 8];
    unsigned short* lb1 = &Bs[(r + 64) * 32 + kc * 8];

    const f32x4 zero = {0.f, 0.f, 0.f, 0.f};
    f32x4 acc[4][4];
#pragma unroll
    for (int i = 0; i < 4; ++i)
#pragma unroll
        for (int j = 0; j < 4; ++j) acc[i][j] = zero;

    const int lm = lane & 15;
    const int q  = lane >> 4;

    for (int k0 = 0; k0 < 1024; k0 += 64) {
#pragma unroll
        for (int s = 0; s < 2; ++s) {
            const int kk = k0 + s * 32;                      // wave-uniform
            const unsigned short* P = (kk < 512) ? X : G;    // A halves, stride 512
            const int kof = (kk & 511) + kc * 8;
            async_ld16(P + (size_t)ar0 * 512 + kof, la0 + s * 4096);
            async_ld16(P + (size_t)ar1 * 512 + kof, la1 + s * 4096);
            async_ld16(B + (size_t)br0 * 1024 + kk + kc * 8, lb0 + s * 4096);
            async_ld16(B + (size_t)br1 * 1024 + kk + kc * 8, lb1 + s * 4096);
        }
        __syncthreads();

        bf16x8 afr[2][4], bfr[2][4];
#pragma unroll
        for (int s = 0; s < 2; ++s) {
#pragma unroll
            for (int mt = 0; mt < 4; ++mt)
                afr[s][mt] = *(const bf16x8*)&As[s * 4096 + (wm + mt * 16 + lm) * 32 + q * 8];
#pragma unroll
            for (int nt = 0; nt < 4; ++nt)
                bfr[s][nt] = *(const bf16x8*)&Bs[s * 4096 + (wn + nt * 16 + lm) * 32 + q * 8];
        }
#pragma unroll
        for (int s = 0; s < 2; ++s)
#pragma unroll
            for (int mt = 0; mt < 4; ++mt)
#pragma unroll
                for (int nt = 0; nt < 4; ++nt)
                    acc[mt][nt] = __builtin_amdgcn_mfma_f32_16x16x32_bf16(afr[s][mt], bfr[s][nt],
                                                                          acc[mt][nt], 0, 0, 0);
        __syncthreads();
    }

    // epilogue: C/D layout col=lane&15, row=(lane>>4)*4+reg (m89-verified)
#pragma unroll
    for (int nt = 0; nt < 4; ++nt) {
        const int col = bn * 128 + wn + nt * 16 + lm;
        const float bv = bias[col];
        float bn_inv = 0.f, bn_mb = 0.f, bn_beta = 0.f;
        if (!last) {
            bn_inv = gamma[col] * rsqrtf(var[col] + EPS);
            bn_mb  = mean[col];
            bn_beta = beta[col];
        }
#pragma unroll
        for (int mt = 0; mt < 4; ++mt) {
            const int row0 = bm * 128 + wm + mt * 16 + q * 4;
#pragma unroll
            for (int i = 0; i < 4; ++i) {
                const int row = row0 + i;
                if (row < M) {
                    float v = acc[mt][nt][i] + bv;
                    v = v > 0.f ? v : 0.f;
                    if (last) {
                        C[(size_t)row * 512 + col] = v;
                    } else {
                        const float y = (v - bn_mb) * bn_inv + bn_beta;
                        Y[(size_t)row * 512 + col] = f2bf(y);
                    }
                }
            }
        }
    }
}

extern "C" void kernel_launch(void* const* d_in, const int* in_sizes, int n_in,
                              void* d_out, int out_size, void* d_ws, size_t ws_size,
                              hipStream_t stream) {
    const int*   tokens = (const int*)d_in[0];
    const int*   posi   = (const int*)d_in[1];
    const int*   ei     = (const int*)d_in[2];
    const float* vemb   = (const float*)d_in[3];
    const float* pemb   = (const float*)d_in[4];
    const float* gamma  = (const float*)d_in[5];
    const float* beta   = (const float*)d_in[6];
    const float* mean   = (const float*)d_in[7];
    const float* var    = (const float*)d_in[8];
    const float* Wrel   = (const float*)d_in[9];
    const float* brel   = (const float*)d_in[10];
    const float* Wroot  = (const float*)d_in[11];

    const int N = in_sizes[0];
    const int E = in_sizes[2] / 2;
    float* out = (float*)d_out;

    // layout: front (CSR) | X0 | G | Wcat | [X1 if ws permits]
    char* w = (char*)d_ws;
    int*      deg     = (int*)(w);
    int*      offsets = (int*)(w + 80000);
    int*      cursor  = (int*)(w + 160016);
    float*    deginv  = (float*)(w + 240032);
    int*      csr     = (int*)(w + 320048);
    uint32_t* X0      = (uint32_t*)(w + 1600064);   // [N][256] uints = [N][512] bf16
    uint32_t* G       = (uint32_t*)(w + 22080064);  // [N][256] uints
    uint32_t* Wcat    = (uint32_t*)(w + 42560064);  // [512][512] uints = [512][1024] bf16
    uint32_t* X1      = (uint32_t*)(w + 43608640);  // second X buffer (ping-pong)
    const bool big = ws_size >= (size_t)43608640 + 20480000;

    zero_kernel<<<(N + 255) / 256, 256, 0, stream>>>(deg, N);
    count_kernel<<<(E + 255) / 256, 256, 0, stream>>>(ei, deg, E);
    scan_kernel<<<1, 1024, 0, stream>>>(deg, offsets, cursor, deginv, N);
    fill_kernel<<<(E + 255) / 256, 256, 0, stream>>>(ei, cursor, csr, E);

    embed_bn_kernel<<<(N * 128 + 255) / 256, 256, 0, stream>>>(
        tokens, posi, vemb, pemb, gamma, beta, mean, var, X0, N);

    uint32_t* X = X0;
    uint32_t* Y = big ? X1 : X0;    // fallback: in-place if ws too small
    for (int l = 0; l < 4; ++l) {
        const int last = (l == 3);
        castW_kernel<<<1024, 256, 0, stream>>>(Wroot + (size_t)l * 262144,
                                               Wrel + (size_t)l * 262144, Wcat);
        aggregate_kernel<<<8 * ((N + 3) / 4), 256, 0, stream>>>(X, G, offsets, csr, deginv, N);
        gemm_bt_bias_relu<<<dim3(4, (N + 127) / 128), 256, 0, stream>>>(
            (const unsigned short*)X, (const unsigned short*)G,
            (const unsigned short*)Wcat, brel + l * 512,
            gamma + (l + 1) * 512, beta + (l + 1) * 512,
            mean + (l + 1) * 512, var + (l + 1) * 512,
            last, out, (unsigned short*)Y, N);
        uint32_t* tmp = X; X = Y; Y = tmp;
    }
}

// Round 7
// 571.080 us; speedup vs baseline: 1.4185x; 1.1206x over previous
//
#include <hip/hip_runtime.h>
#include <cstdint>

#define EPS 1e-5f

typedef __attribute__((ext_vector_type(8))) short bf16x8;   // 8 bf16 in 4 VGPRs
typedef __attribute__((ext_vector_type(4))) float f32x4;

// ---------- bf16 helpers (RNE) ----------
__device__ __forceinline__ unsigned short f2bf(float x) {
    uint32_t u = __float_as_uint(x);
    u += 0x7fffu + ((u >> 16) & 1u);
    return (unsigned short)(u >> 16);
}
__device__ __forceinline__ uint32_t pack2(float lo, float hi) {
    return (uint32_t)f2bf(lo) | ((uint32_t)f2bf(hi) << 16);
}
__device__ __forceinline__ float bflo(uint32_t p) { return __uint_as_float(p << 16); }
__device__ __forceinline__ float bfhi(uint32_t p) { return __uint_as_float(p & 0xffff0000u); }

// ---------- async global->LDS, 16B per lane ----------
__device__ __forceinline__ void async_ld16(const void* g, const void* l) {
    __builtin_amdgcn_global_load_lds(
        (const __attribute__((address_space(1))) uint32_t*)(uintptr_t)g,
        (__attribute__((address_space(3))) uint32_t*)(uint32_t)(uintptr_t)l,
        16, 0, 0);
}

// ---------- CSR build ----------
__global__ __launch_bounds__(256) void zero_kernel(int* __restrict__ p, int n) {
    int i = blockIdx.x * 256 + threadIdx.x;
    if (i < n) p[i] = 0;
}

__global__ __launch_bounds__(256) void count_kernel(const int* __restrict__ ei,
                                                    int* __restrict__ deg, int E) {
    int e = blockIdx.x * 256 + threadIdx.x;
    if (e < E) atomicAdd(&deg[ei[E + e]], 1);
}

__global__ __launch_bounds__(1024) void scan_kernel(const int* __restrict__ deg,
                                                    int* __restrict__ offsets,
                                                    int* __restrict__ cursor,
                                                    float* __restrict__ deginv, int N) {
    __shared__ int part[1024];
    const int t = threadIdx.x;
    const int CH = (N + 1023) >> 10;
    const int base = t * CH;
    int s = 0;
    for (int j = 0; j < CH; ++j) {
        int idx = base + j;
        if (idx < N) s += deg[idx];
    }
    part[t] = s;
    __syncthreads();
    for (int off = 1; off < 1024; off <<= 1) {
        int add = (t >= off) ? part[t - off] : 0;
        __syncthreads();
        part[t] += add;
        __syncthreads();
    }
    int run = (t == 0) ? 0 : part[t - 1];
    for (int j = 0; j < CH; ++j) {
        int idx = base + j;
        if (idx < N) {
            offsets[idx] = run;
            cursor[idx]  = run;
            int dgi = deg[idx];
            deginv[idx] = 1.0f / (float)(dgi > 0 ? dgi : 1);
            run += dgi;
        }
    }
    if (t == 1023) offsets[N] = run;
}

__global__ __launch_bounds__(256) void fill_kernel(const int* __restrict__ ei,
                                                   int* __restrict__ cursor,
                                                   int* __restrict__ csr, int E) {
    int e = blockIdx.x * 256 + threadIdx.x;
    if (e < E) {
        int dd = ei[E + e];
        int slot = atomicAdd(&cursor[dd], 1);
        csr[slot] = ei[e];
    }
}

// ---------- embedding + BN(layer 0), bf16 into X[N][512] ----------
__global__ __launch_bounds__(256) void embed_bn_kernel(const int* __restrict__ tok,
                                                       const int* __restrict__ pos,
                                                       const float* __restrict__ vemb,
                                                       const float* __restrict__ pemb,
                                                       const float* __restrict__ gamma,
                                                       const float* __restrict__ beta,
                                                       const float* __restrict__ mean,
                                                       const float* __restrict__ var,
                                                       uint32_t* __restrict__ X, int N) {
    const int idx = blockIdx.x * 256 + threadIdx.x;
    if (idx >= N * 128) return;
    const int row = idx >> 7;
    const int c = (idx & 127) * 4;
    const int tk = tok[row];
    const int ps = pos[row];
    const float4 a = *(const float4*)&vemb[(size_t)tk * 512 + c];
    const float4 b = *(const float4*)&pemb[(size_t)ps * 512 + c];
    const float4 g = *(const float4*)&gamma[c];
    const float4 be = *(const float4*)&beta[c];
    const float4 mn = *(const float4*)&mean[c];
    const float4 vr = *(const float4*)&var[c];
    const float y0 = (a.x + b.x - mn.x) * (g.x * rsqrtf(vr.x + EPS)) + be.x;
    const float y1 = (a.y + b.y - mn.y) * (g.y * rsqrtf(vr.y + EPS)) + be.y;
    const float y2 = (a.z + b.z - mn.z) * (g.z * rsqrtf(vr.z + EPS)) + be.z;
    const float y3 = (a.w + b.w - mn.w) * (g.w * rsqrtf(vr.w + EPS)) + be.w;
    uint2 o;
    o.x = pack2(y0, y1);
    o.y = pack2(y2, y3);
    *(uint2*)&X[(size_t)row * 256 + (c >> 1)] = o;
}

// ---------- per-layer: W_cat bf16 [512 rows][1024 k] = [W_root | W_rel] (B^T layout) ----------
__global__ __launch_bounds__(256) void castW_kernel(const float* __restrict__ Wroot,
                                                    const float* __restrict__ Wrel,
                                                    uint32_t* __restrict__ Wcat) {
    const int p = blockIdx.x * 256 + threadIdx.x;
    const int o  = p >> 9;
    const int dp = p & 511;
    float2 v;
    if (dp < 256) v = *(const float2*)&Wroot[(size_t)o * 512 + dp * 2];
    else          v = *(const float2*)&Wrel[(size_t)o * 512 + (dp - 256) * 2];
    Wcat[(size_t)o * 512 + dp] = pack2(v.x, v.y);
}

// ---------- mean aggregation (R2 structure, wave-per-node, 16 outstanding dwordx4) ----------
__global__ __launch_bounds__(256) void aggregate_kernel(const uint32_t* __restrict__ X,
                                                        uint32_t* __restrict__ G,
                                                        const int* __restrict__ offsets,
                                                        const int* __restrict__ csr,
                                                        const float* __restrict__ deginv,
                                                        int N) {
    const int node = blockIdx.x * 4 + (threadIdx.x >> 6);
    if (node >= N) return;
    const int lane = threadIdx.x & 63;
    const int col = lane * 4;                 // uint index within the 256-uint row
    const int beg = offsets[node];
    const int end = offsets[node + 1];
    float s[8] = {0.f, 0.f, 0.f, 0.f, 0.f, 0.f, 0.f, 0.f};
    int e = beg;
    for (; e + 16 <= end; e += 16) {
        uint4 p[16];
#pragma unroll
        for (int j = 0; j < 16; ++j) {
            const int ij = csr[e + j];
            p[j] = *(const uint4*)&X[(size_t)ij * 256 + col];
        }
#pragma unroll
        for (int j = 0; j < 16; ++j) {
            s[0] += bflo(p[j].x); s[1] += bfhi(p[j].x);
            s[2] += bflo(p[j].y); s[3] += bfhi(p[j].y);
            s[4] += bflo(p[j].z); s[5] += bfhi(p[j].z);
            s[6] += bflo(p[j].w); s[7] += bfhi(p[j].w);
        }
    }
    for (; e + 4 <= end; e += 4) {
        uint4 p[4];
#pragma unroll
        for (int j = 0; j < 4; ++j) {
            const int ij = csr[e + j];
            p[j] = *(const uint4*)&X[(size_t)ij * 256 + col];
        }
#pragma unroll
        for (int j = 0; j < 4; ++j) {
            s[0] += bflo(p[j].x); s[1] += bfhi(p[j].x);
            s[2] += bflo(p[j].y); s[3] += bfhi(p[j].y);
            s[4] += bflo(p[j].z); s[5] += bfhi(p[j].z);
            s[6] += bflo(p[j].w); s[7] += bfhi(p[j].w);
        }
    }
    for (; e < end; ++e) {
        const int i0 = csr[e];
        const uint4 p0 = *(const uint4*)&X[(size_t)i0 * 256 + col];
        s[0] += bflo(p0.x); s[1] += bfhi(p0.x);
        s[2] += bflo(p0.y); s[3] += bfhi(p0.y);
        s[4] += bflo(p0.z); s[5] += bfhi(p0.z);
        s[6] += bflo(p0.w); s[7] += bfhi(p0.w);
    }
    const float inv = deginv[node];
    uint4 o;
    o.x = pack2(s[0] * inv, s[1] * inv);
    o.y = pack2(s[2] * inv, s[3] * inv);
    o.z = pack2(s[4] * inv, s[5] * inv);
    o.w = pack2(s[6] * inv, s[7] * inv);
    *(uint4*)&G[(size_t)node * 256 + col] = o;
}

// ---------- GEMM: out = relu([X|G][M,1024] @ Wcat[512,1024]^T + bias) ----------
// 64x128 tile, BK=64 (two BK=32 stages), grid (4, M/64) = 1252 blocks (~4.9/CU):
// more co-resident blocks so other blocks' MFMA covers each block's barrier drain.
// 4 waves; wave w owns all 64 rows x cols [w*32, w*32+32) -> acc 4x2 f32x4.
__global__ __launch_bounds__(256) void gemm_bt_bias_relu(const unsigned short* __restrict__ X,
                                                         const unsigned short* __restrict__ G,
                                                         const unsigned short* __restrict__ B,
                                                         const float* __restrict__ bias,
                                                         const float* __restrict__ gamma,
                                                         const float* __restrict__ beta,
                                                         const float* __restrict__ mean,
                                                         const float* __restrict__ var,
                                                         int last,
                                                         float* __restrict__ C,
                                                         unsigned short* __restrict__ Y,
                                                         int M) {
    __shared__ __align__(16) unsigned short As[2 * 64 * 32];    // stage s at +s*2048 shorts
    __shared__ __align__(16) unsigned short Bs[2 * 128 * 32];   // stage s at +s*4096 shorts

    const int t    = threadIdx.x;
    const int lane = t & 63;
    const int wave = t >> 6;
    const int bm = blockIdx.y;
    const int bn = blockIdx.x;
    const int lm = lane & 15;
    const int q  = lane >> 4;

    const int r  = t >> 2;   // 0..63
    const int kc = t & 3;
    int ar = bm * 64 + r; if (ar >= M) ar = M - 1;
    const int br0 = bn * 128 + r;        // < 512
    const int br1 = br0 + 64;

    unsigned short* la  = &As[r * 32 + kc * 8];          // byte off == t*16
    unsigned short* lb0 = &Bs[r * 32 + kc * 8];
    unsigned short* lb1 = &Bs[(r + 64) * 32 + kc * 8];

    const f32x4 zero = {0.f, 0.f, 0.f, 0.f};
    f32x4 acc[4][2];
#pragma unroll
    for (int i = 0; i < 4; ++i)
#pragma unroll
        for (int j = 0; j < 2; ++j) acc[i][j] = zero;

    for (int k0 = 0; k0 < 1024; k0 += 64) {
#pragma unroll
        for (int s = 0; s < 2; ++s) {
            const int kk = k0 + s * 32;                      // wave-uniform
            const unsigned short* P = (kk < 512) ? X : G;    // A halves, stride 512
            const int kof = (kk & 511) + kc * 8;
            async_ld16(P + (size_t)ar * 512 + kof, la + s * 2048);
            async_ld16(B + (size_t)br0 * 1024 + kk + kc * 8, lb0 + s * 4096);
            async_ld16(B + (size_t)br1 * 1024 + kk + kc * 8, lb1 + s * 4096);
        }
        __syncthreads();

        bf16x8 afr[2][4], bfr[2][2];
#pragma unroll
        for (int s = 0; s < 2; ++s) {
#pragma unroll
            for (int mt = 0; mt < 4; ++mt)
                afr[s][mt] = *(const bf16x8*)&As[s * 2048 + (mt * 16 + lm) * 32 + q * 8];
#pragma unroll
            for (int nt = 0; nt < 2; ++nt)
                bfr[s][nt] = *(const bf16x8*)&Bs[s * 4096 + (wave * 32 + nt * 16 + lm) * 32 + q * 8];
        }
#pragma unroll
        for (int s = 0; s < 2; ++s)
#pragma unroll
            for (int mt = 0; mt < 4; ++mt)
#pragma unroll
                for (int nt = 0; nt < 2; ++nt)
                    acc[mt][nt] = __builtin_amdgcn_mfma_f32_16x16x32_bf16(afr[s][mt], bfr[s][nt],
                                                                          acc[mt][nt], 0, 0, 0);
        __syncthreads();
    }

    // epilogue: C/D layout col=lane&15, row=(lane>>4)*4+reg (m89-verified)
#pragma unroll
    for (int nt = 0; nt < 2; ++nt) {
        const int col = bn * 128 + wave * 32 + nt * 16 + lm;
        const float bv = bias[col];
        float bn_inv = 0.f, bn_mb = 0.f, bn_beta = 0.f;
        if (!last) {
            bn_inv = gamma[col] * rsqrtf(var[col] + EPS);
            bn_mb  = mean[col];
            bn_beta = beta[col];
        }
#pragma unroll
        for (int mt = 0; mt < 4; ++mt) {
            const int row0 = bm * 64 + mt * 16 + q * 4;
#pragma unroll
            for (int i = 0; i < 4; ++i) {
                const int row = row0 + i;
                if (row < M) {
                    float v = acc[mt][nt][i] + bv;
                    v = v > 0.f ? v : 0.f;
                    if (last) {
                        C[(size_t)row * 512 + col] = v;
                    } else {
                        const float y = (v - bn_mb) * bn_inv + bn_beta;
                        Y[(size_t)row * 512 + col] = f2bf(y);
                    }
                }
            }
        }
    }
}

extern "C" void kernel_launch(void* const* d_in, const int* in_sizes, int n_in,
                              void* d_out, int out_size, void* d_ws, size_t ws_size,
                              hipStream_t stream) {
    const int*   tokens = (const int*)d_in[0];
    const int*   posi   = (const int*)d_in[1];
    const int*   ei     = (const int*)d_in[2];
    const float* vemb   = (const float*)d_in[3];
    const float* pemb   = (const float*)d_in[4];
    const float* gamma  = (const float*)d_in[5];
    const float* beta   = (const float*)d_in[6];
    const float* mean   = (const float*)d_in[7];
    const float* var    = (const float*)d_in[8];
    const float* Wrel   = (const float*)d_in[9];
    const float* brel   = (const float*)d_in[10];
    const float* Wroot  = (const float*)d_in[11];

    const int N = in_sizes[0];
    const int E = in_sizes[2] / 2;
    float* out = (float*)d_out;

    // layout: front (CSR) | X0 | G | Wcat | [X1 if ws permits]
    char* w = (char*)d_ws;
    int*      deg     = (int*)(w);
    int*      offsets = (int*)(w + 80000);
    int*      cursor  = (int*)(w + 160016);
    float*    deginv  = (float*)(w + 240032);
    int*      csr     = (int*)(w + 320048);
    uint32_t* X0      = (uint32_t*)(w + 1600064);   // [N][256] uints = [N][512] bf16
    uint32_t* G       = (uint32_t*)(w + 22080064);  // [N][256] uints
    uint32_t* Wcat    = (uint32_t*)(w + 42560064);  // [512][512] uints = [512][1024] bf16
    uint32_t* X1      = (uint32_t*)(w + 43608640);  // second X buffer (ping-pong)
    const bool big = ws_size >= (size_t)43608640 + 20480000;

    zero_kernel<<<(N + 255) / 256, 256, 0, stream>>>(deg, N);
    count_kernel<<<(E + 255) / 256, 256, 0, stream>>>(ei, deg, E);
    scan_kernel<<<1, 1024, 0, stream>>>(deg, offsets, cursor, deginv, N);
    fill_kernel<<<(E + 255) / 256, 256, 0, stream>>>(ei, cursor, csr, E);

    embed_bn_kernel<<<(N * 128 + 255) / 256, 256, 0, stream>>>(
        tokens, posi, vemb, pemb, gamma, beta, mean, var, X0, N);

    uint32_t* X = X0;
    uint32_t* Y = big ? X1 : X0;    // fallback: in-place if ws too small
    for (int l = 0; l < 4; ++l) {
        const int last = (l == 3);
        castW_kernel<<<1024, 256, 0, stream>>>(Wroot + (size_t)l * 262144,
                                               Wrel + (size_t)l * 262144, Wcat);
        aggregate_kernel<<<(N + 3) / 4, 256, 0, stream>>>(X, G, offsets, csr, deginv, N);
        gemm_bt_bias_relu<<<dim3(4, (N + 63) / 64), 256, 0, stream>>>(
            (const unsigned short*)X, (const unsigned short*)G,
            (const unsigned short*)Wcat, brel + l * 512,
            gamma + (l + 1) * 512, beta + (l + 1) * 512,
            mean + (l + 1) * 512, var + (l + 1) * 512,
            last, out, (unsigned short*)Y, N);
        uint32_t* tmp = X; X = Y; Y = tmp;
    }
}